// Round 16
// baseline (496.511 us; speedup 1.0000x reference)
//
#include <hip/hip_runtime.h>
#include <hip/hip_bf16.h>
#include <stdint.h>

// MoE FFN: B=2,T=2048,D=1024,F=4096,E=8,K=2. S=4096 tokens, 8192 assignments.
#define S_TOK 4096
#define DDIM  1024
#define FDIM  4096
#define EEXP  8
#define CAP   (S_TOK * 2)

typedef __bf16 bf16x8 __attribute__((ext_vector_type(8)));
typedef __bf16 bf16x4 __attribute__((ext_vector_type(4)));
typedef float  f32x4  __attribute__((ext_vector_type(4)));

__device__ __forceinline__ unsigned short f2bf(float f) {
    union { float f; unsigned u; } v; v.f = f;
    unsigned u = v.u;
    return (unsigned short)((u + 0x7FFFu + ((u >> 16) & 1u)) >> 16);  // RNE
}

// global -> LDS async copy, 16B/lane. Offset arg MUST stay 0 (r8 lesson).
__device__ __forceinline__ void gload16(const void* g, void* l) {
    auto gp = reinterpret_cast<const __attribute__((address_space(1))) uint32_t*>(
        reinterpret_cast<uintptr_t>(g));
    auto lp = reinterpret_cast<__attribute__((address_space(3))) uint32_t*>(
        static_cast<uint32_t>(reinterpret_cast<uintptr_t>(l)));
    __builtin_amdgcn_global_load_lds(gp, lp, 16, 0, 0);
}

// ---------------- small kernels ----------------

__global__ void zero_k(int* p, int n) {
    int i = threadIdx.x;
    if (i < n) p[i] = 0;
}

__global__ void cvt_bf16(const float* __restrict__ src, unsigned short* __restrict__ dst, int n4) {
    int stride = gridDim.x * blockDim.x;
    for (int i = blockIdx.x * blockDim.x + threadIdx.x; i < n4; i += stride) {
        float4 v = ((const float4*)src)[i];
        bf16x4 o = { (__bf16)v.x, (__bf16)v.y, (__bf16)v.z, (__bf16)v.w };
        ((bf16x4*)dst)[i] = o;
    }
}

// Router: one wave per token, fp32 (must match numpy top-2 selection). Fused x->bf16.
__global__ void router_k(const float* __restrict__ x, const float* __restrict__ gw,
                         unsigned short* __restrict__ xb,
                         int* __restrict__ topk_e, float* __restrict__ topk_g,
                         int* __restrict__ counts) {
    int s = blockIdx.x;
    int l = threadIdx.x;
    const float* xr = x + (size_t)s * DDIM;
    unsigned short* xbr = xb + (size_t)s * DDIM;
    float acc[EEXP];
#pragma unroll
    for (int e = 0; e < EEXP; ++e) acc[e] = 0.f;
    for (int i = 0; i < DDIM; i += 64) {
        float xv = xr[i + l];
        xbr[i + l] = f2bf(xv);
#pragma unroll
        for (int e = 0; e < EEXP; ++e) acc[e] = fmaf(xv, gw[e * DDIM + i + l], acc[e]);
    }
#pragma unroll
    for (int e = 0; e < EEXP; ++e)
        for (int off = 32; off > 0; off >>= 1) acc[e] += __shfl_down(acc[e], off, 64);
    if (l == 0) {
        float v0 = -1e30f, v1 = -1e30f; int i0 = 0, i1 = 0;
#pragma unroll
        for (int e = 0; e < EEXP; ++e) {
            float v = acc[e];
            if (v > v0)      { v1 = v0; i1 = i0; v0 = v; i0 = e; }
            else if (v > v1) { v1 = v;  i1 = e; }
        }
        float t = expf(v1 - v0);
        float d = 1.f + t;
        topk_e[2 * s] = i0; topk_e[2 * s + 1] = i1;
        topk_g[2 * s] = 1.f / d; topk_g[2 * s + 1] = t / d;
        atomicAdd(&counts[i0], 1);
        atomicAdd(&counts[i1], 1);
    }
}

__global__ void scan_k(const int* __restrict__ counts, int* __restrict__ basep) {
    if (threadIdx.x == 0) {
        int b = 0;
        for (int e = 0; e < EEXP; ++e) { basep[e] = b; b += counts[e]; }
    }
}

__global__ void scatter_k(const int* __restrict__ topk_e, int* __restrict__ rankctr,
                          const int* __restrict__ basep, int* __restrict__ arena_token,
                          int* __restrict__ pos_of) {
    int s = blockIdx.x * blockDim.x + threadIdx.x;
    if (s >= S_TOK) return;
#pragma unroll
    for (int t = 0; t < 2; ++t) {
        int e = topk_e[2 * s + t];
        int r = atomicAdd(&rankctr[e], 1);
        int p = basep[e] + r;
        arena_token[p] = s;
        pos_of[2 * s + t] = p;
    }
}

// ---------------- MFMA GEMM: m97-clone. BM=BN=128, BK=32, 4 waves, single 16KB buffer ----
// Cross-round model (r7/r11/r13/r15 vs verified m97): staging rate ≈ 5-7 B/cyc/CU PER
// RESIDENT BLOCK, regardless of pipeline depth / source pattern / LDS image. m97 (verified
// 21.8 B/cyc/CU) = 3+ blocks/CU of 4 waves with a plain single-buffer 2-barrier loop.
// This kernel: 16KB LDS, ~105 VGPR, launch_bounds(256,4) -> 4-5 blocks/CU.
// Loop: STG(4 gload16/thread-group) -> syncthreads -> ds_read+16 MFMA -> syncthreads.
// Linear LDS + linear frag reads (bank conflicts accepted: compute path ~10us, r10 ablation).
template <int EPI>
__global__ __launch_bounds__(256, 4) void moe_gemm(
    const unsigned short* __restrict__ Asrc, const unsigned short* __restrict__ Bw,
    const float* __restrict__ bias, unsigned short* __restrict__ hOut,
    float* __restrict__ fOut0, float* __restrict__ fOut1,
    const int* __restrict__ arena_token, const int* __restrict__ counts,
    const int* __restrict__ basep, int Kd, int Nd, int ny, int nx, int Klen) {
    int cpx = gridDim.x >> 3;
    int bid = blockIdx.x;
    int wid = (bid & 7) * cpx + (bid >> 3);
    int my  = wid % ny;
    int q   = wid / ny;
    int e   = q % EEXP;
    int r2  = q / EEXP;
    int n   = r2 % nx;
    int ks  = r2 / nx;

    int count = counts[e];
    int m0 = my * 128;
    if (m0 >= count) return;
    int base = basep[e];
    int n0 = n * 128;
    int kbase = ks * Klen;
    int tid = threadIdx.x, w = tid >> 6, l = tid & 63;

    float* fo = ks ? fOut1 : fOut0;

    // A 8KB @0 (rows 0..127 x 64B), B 8KB @8192.
    __shared__ __align__(16) char smem[16384];

    // ---- stage pointers: per-thread rows, 16B chunk (tid&3); bumped +32 elem/K-step ----
    const unsigned short *pA0, *pA1, *pB0, *pB1;
    {
        int r0 = m0 + (tid >> 2);                    // rows 0..63
        int r1 = r0 + 64;                            // rows 64..127
        int c0 = (r0 < count) ? r0 : (count - 1);
        int c1 = (r1 < count) ? r1 : (count - 1);
        int ch = (tid & 3) * 8;                      // element offset in K-tile
        if (EPI == 1) {
            pA0 = Asrc + (size_t)arena_token[base + c0] * Kd + kbase + ch;
            pA1 = Asrc + (size_t)arena_token[base + c1] * Kd + kbase + ch;
        } else {
            pA0 = Asrc + (size_t)(base + c0) * Kd + kbase + ch;
            pA1 = Asrc + (size_t)(base + c1) * Kd + kbase + ch;
        }
        pB0 = Bw + ((size_t)e * Nd + n0 + (tid >> 2)) * Kd + kbase + ch;
        pB1 = Bw + ((size_t)e * Nd + n0 + 64 + (tid >> 2)) * Kd + kbase + ch;
    }

#define STG() do {                                                     \
        gload16(pA0, smem + w * 1024);                                 \
        gload16(pA1, smem + 4096 + w * 1024);                          \
        gload16(pB0, smem + 8192 + w * 1024);                          \
        gload16(pB1, smem + 12288 + w * 1024);                         \
        pA0 += 32; pA1 += 32; pB0 += 32; pB1 += 32;                    \
    } while (0)

    // ---- fragment read addressing (linear; wave-tile 64x64, 2x2 waves) ----
    int wm = w >> 1, wn = w & 1;
    int hi = l >> 4;
    const char* Ar = smem + (size_t)(wm * 64 + (l & 15)) * 64 + hi * 16;
    const char* Br = smem + 8192 + (size_t)(wn * 64 + (l & 15)) * 64 + hi * 16;

    f32x4 acc[4][4];
#pragma unroll
    for (int i = 0; i < 4; ++i)
#pragma unroll
        for (int j = 0; j < 4; ++j) acc[i][j] = (f32x4){0.f, 0.f, 0.f, 0.f};

    int nt = Klen >> 5;
    for (int t = 0; t < nt; ++t) {
        STG();
        __syncthreads();   // drains vmcnt(0): tile landed for all waves
        bf16x8 bq[4];
#pragma unroll
        for (int ni = 0; ni < 4; ++ni) bq[ni] = *(const bf16x8*)(Br + ni * 1024);
#pragma unroll
        for (int mi = 0; mi < 4; ++mi) {
            bf16x8 a = *(const bf16x8*)(Ar + mi * 1024);
#pragma unroll
            for (int ni = 0; ni < 4; ++ni)
                acc[mi][ni] = __builtin_amdgcn_mfma_f32_16x16x32_bf16(a, bq[ni], acc[mi][ni], 0, 0, 0);
        }
        __syncthreads();   // reads done before next STG overwrites
    }
#undef STG

    // Epilogue. C/D layout: col = lane&15, row = (lane>>4)*4 + reg  [m89 verified]
#pragma unroll
    for (int mi = 0; mi < 4; ++mi)
#pragma unroll
        for (int ni = 0; ni < 4; ++ni)
#pragma unroll
            for (int r = 0; r < 4; ++r) {
                int rl = wm * 64 + mi * 16 + hi * 4 + r;
                int gr = m0 + rl;
                if (gr < count) {
                    int col = n0 + wn * 64 + ni * 16 + (l & 15);
                    float v = acc[mi][ni][r];
                    if (EPI == 1) {
                        v += bias[e * Nd + col];
                        v = fmaxf(v, 0.f);
                        hOut[(size_t)(base + gr) * Nd + col] = f2bf(v);
                    } else {
                        fo[(size_t)(base + gr) * Nd + col] = v;
                    }
                }
            }
}

// Deterministic combine with 2 K-split partials (separate regions).
__global__ void combine_k(const float* __restrict__ P0, const float* __restrict__ P1,
                          const float* __restrict__ b2,
                          const int* __restrict__ topk_e, const float* __restrict__ topk_g,
                          const int* __restrict__ pos_of, float* __restrict__ y) {
    int idx = blockIdx.x * blockDim.x + threadIdx.x;
    int s = idx >> 8;
    int c = (idx & 255) * 4;
    int e0 = topk_e[2 * s], e1 = topk_e[2 * s + 1];
    float g0 = topk_g[2 * s], g1 = topk_g[2 * s + 1];
    int p0 = pos_of[2 * s], p1 = pos_of[2 * s + 1];
    float4 a0 = *(const float4*)(P0 + (size_t)p0 * DDIM + c);
    float4 a1 = *(const float4*)(P1 + (size_t)p0 * DDIM + c);
    float4 b0v = *(const float4*)(P0 + (size_t)p1 * DDIM + c);
    float4 b1v = *(const float4*)(P1 + (size_t)p1 * DDIM + c);
    float4 c0 = *(const float4*)(b2 + (size_t)e0 * DDIM + c);
    float4 c1 = *(const float4*)(b2 + (size_t)e1 * DDIM + c);
    float4 r;
    r.x = g0 * (a0.x + a1.x + c0.x) + g1 * (b0v.x + b1v.x + c1.x);
    r.y = g0 * (a0.y + a1.y + c0.y) + g1 * (b0v.y + b1v.y + c1.y);
    r.z = g0 * (a0.z + a1.z + c0.z) + g1 * (b0v.z + b1v.z + c1.z);
    r.w = g0 * (a0.w + a1.w + c0.w) + g1 * (b0v.w + b1v.w + c1.w);
    *(float4*)(y + (size_t)s * DDIM + c) = r;
}

extern "C" void kernel_launch(void* const* d_in, const int* in_sizes, int n_in,
                              void* d_out, int out_size, void* d_ws, size_t ws_size,
                              hipStream_t stream) {
    const float* x      = (const float*)d_in[0];
    const float* gate_w = (const float*)d_in[1];
    const float* w1     = (const float*)d_in[2];
    const float* b1     = (const float*)d_in[3];
    const float* w2     = (const float*)d_in[4];
    const float* b2     = (const float*)d_in[5];

    char* p = (char*)d_ws;
    unsigned short* w1b = (unsigned short*)p;   // 64 MB; reused as partial0 (33.6MB) after G1
    float* part0        = (float*)p;            p += (size_t)EEXP * FDIM * DDIM * 2;
    unsigned short* w2b = (unsigned short*)p;   p += (size_t)EEXP * FDIM * DDIM * 2;  // 64 MB
    unsigned short* xb  = (unsigned short*)p;   p += (size_t)S_TOK * DDIM * 2;        //  8 MB
    unsigned short* hA  = (unsigned short*)p;   p += (size_t)CAP * FDIM * 2;          // 64 MB
    float* part1        = (float*)p;            p += (size_t)CAP * DDIM * 4;          // 33.6 MB
    int*   topk_e       = (int*)p;              p += S_TOK * 2 * 4;
    float* topk_g       = (float*)p;            p += S_TOK * 2 * 4;
    int*   pos_of       = (int*)p;              p += S_TOK * 2 * 4;
    int*   arena_token  = (int*)p;              p += CAP * 4;
    int*   counts       = (int*)p;              p += 64;
    int*   rankctr      = (int*)p;              p += 64;
    int*   basep        = (int*)p;              p += 64;
    (void)ws_size; (void)in_sizes; (void)n_in; (void)out_size;

    zero_k<<<1, 64, 0, stream>>>(counts, 48);

    cvt_bf16<<<4096, 256, 0, stream>>>(w1, w1b, EEXP * FDIM * DDIM / 4);
    cvt_bf16<<<4096, 256, 0, stream>>>(w2, w2b, EEXP * FDIM * DDIM / 4);

    router_k<<<S_TOK, 64, 0, stream>>>(x, gate_w, xb, topk_e, topk_g, counts);
    scan_k<<<1, 1, 0, stream>>>(counts, basep);
    scatter_k<<<S_TOK / 256, 256, 0, stream>>>(topk_e, rankctr, basep, arena_token, pos_of);

    // GEMM1: BM=BN=128. grid = ny(32) * E(8) * nx(32) = 8192 (active ~2048 = 8/CU).
    moe_gemm<1><<<dim3(32 * EEXP * 32), 256, 0, stream>>>(
        xb, w1b, b1, hA, nullptr, nullptr, arena_token, counts, basep,
        DDIM, FDIM, 32, 32, DDIM);
    // GEMM2: K=4096 split 2. grid = ny(32) * E(8) * nx(8) * KS(2) = 4096 (active ~1024 = 4/CU).
    moe_gemm<2><<<dim3(32 * EEXP * 8 * 2), 256, 0, stream>>>(
        hA, w2b, nullptr, nullptr, part0, part1, arena_token, counts, basep,
        FDIM, DDIM, 32, 8, FDIM / 2);

    combine_k<<<S_TOK * DDIM / 4 / 256, 256, 0, stream>>>(
        part0, part1, b2, topk_e, topk_g, pos_of, (float*)d_out);
}

// Round 17
// 445.272 us; speedup vs baseline: 1.1151x; 1.1151x over previous
//
#include <hip/hip_runtime.h>
#include <hip/hip_bf16.h>
#include <stdint.h>

// MoE FFN: B=2,T=2048,D=1024,F=4096,E=8,K=2. S=4096 tokens, 8192 assignments.
#define S_TOK 4096
#define DDIM  1024
#define FDIM  4096
#define EEXP  8
#define CAP   (S_TOK * 2)
#define BUF   24576

typedef __bf16 bf16x8 __attribute__((ext_vector_type(8)));
typedef __bf16 bf16x4 __attribute__((ext_vector_type(4)));
typedef float  f32x4  __attribute__((ext_vector_type(4)));

__device__ __forceinline__ unsigned short f2bf(float f) {
    union { float f; unsigned u; } v; v.f = f;
    unsigned u = v.u;
    return (unsigned short)((u + 0x7FFFu + ((u >> 16) & 1u)) >> 16);  // RNE
}

// global -> LDS async copy, 16B/lane. Offset arg MUST stay 0 (r8 lesson).
__device__ __forceinline__ void gload16(const void* g, void* l) {
    auto gp = reinterpret_cast<const __attribute__((address_space(1))) uint32_t*>(
        reinterpret_cast<uintptr_t>(g));
    auto lp = reinterpret_cast<__attribute__((address_space(3))) uint32_t*>(
        static_cast<uint32_t>(reinterpret_cast<uintptr_t>(l)));
    __builtin_amdgcn_global_load_lds(gp, lp, 16, 0, 0);
}

// ---------------- small kernels ----------------

// Both weight tensors in one launch (same total bytes, one fewer launch gap).
__global__ void cvt_both(const float* __restrict__ w1, const float* __restrict__ w2,
                         unsigned short* __restrict__ w1b, unsigned short* __restrict__ w2b) {
    const int n4 = EEXP * FDIM * DDIM / 4;   // per tensor
    int stride = gridDim.x * blockDim.x;
    for (int i = blockIdx.x * blockDim.x + threadIdx.x; i < 2 * n4; i += stride) {
        const float* src = (i < n4) ? w1 : w2;
        unsigned short* dst = (i < n4) ? w1b : w2b;
        int j = (i < n4) ? i : (i - n4);
        float4 v = ((const float4*)src)[j];
        bf16x4 o = { (__bf16)v.x, (__bf16)v.y, (__bf16)v.z, (__bf16)v.w };
        ((bf16x4*)dst)[j] = o;
    }
}

// Router: one wave per token, fp32 (must match numpy top-2 selection). Fused x->bf16.
__global__ void router_k(const float* __restrict__ x, const float* __restrict__ gw,
                         unsigned short* __restrict__ xb,
                         int* __restrict__ topk_e, float* __restrict__ topk_g,
                         int* __restrict__ counts) {
    int s = blockIdx.x;
    int l = threadIdx.x;
    const float* xr = x + (size_t)s * DDIM;
    unsigned short* xbr = xb + (size_t)s * DDIM;
    float acc[EEXP];
#pragma unroll
    for (int e = 0; e < EEXP; ++e) acc[e] = 0.f;
    for (int i = 0; i < DDIM; i += 64) {
        float xv = xr[i + l];
        xbr[i + l] = f2bf(xv);
#pragma unroll
        for (int e = 0; e < EEXP; ++e) acc[e] = fmaf(xv, gw[e * DDIM + i + l], acc[e]);
    }
#pragma unroll
    for (int e = 0; e < EEXP; ++e)
        for (int off = 32; off > 0; off >>= 1) acc[e] += __shfl_down(acc[e], off, 64);
    if (l == 0) {
        float v0 = -1e30f, v1 = -1e30f; int i0 = 0, i1 = 0;
#pragma unroll
        for (int e = 0; e < EEXP; ++e) {
            float v = acc[e];
            if (v > v0)      { v1 = v0; i1 = i0; v0 = v; i0 = e; }
            else if (v > v1) { v1 = v;  i1 = e; }
        }
        float t = expf(v1 - v0);
        float d = 1.f + t;
        topk_e[2 * s] = i0; topk_e[2 * s + 1] = i1;
        topk_g[2 * s] = 1.f / d; topk_g[2 * s + 1] = t / d;
        atomicAdd(&counts[i0], 1);
        atomicAdd(&counts[i1], 1);
    }
}

__global__ void scan_k(const int* __restrict__ counts, int* __restrict__ basep) {
    if (threadIdx.x == 0) {
        int b = 0;
        for (int e = 0; e < EEXP; ++e) { basep[e] = b; b += counts[e]; }
    }
}

__global__ void scatter_k(const int* __restrict__ topk_e, int* __restrict__ rankctr,
                          const int* __restrict__ basep, int* __restrict__ arena_token,
                          int* __restrict__ pos_of) {
    int s = blockIdx.x * blockDim.x + threadIdx.x;
    if (s >= S_TOK) return;
#pragma unroll
    for (int t = 0; t < 2; ++t) {
        int e = topk_e[2 * s + t];
        int r = atomicAdd(&rankctr[e], 1);
        int p = basep[e] + r;
        arena_token[p] = s;
        pos_of[2 * s + t] = p;
    }
}

// ---------------- MFMA GEMM: BM=128 x BN=256, BK=32, 8 waves, triple-buffer lookahead-2 ----
// r13-proven config (measured optimum across 11 structural variants, r1-r16):
// staging-bound at the chip's ~6 TB/s staged-byte ceiling; 768MB staged volume is the
// feasible minimum at 2 blocks/CU residency (256^2 tiles need the whole reg file). Pipeline:
// 3 slots, lookahead 2, vmcnt(3) steady-state close (never drains), vmcnt(0) tail.
// WAR: slot (t+2)%3 == slot (t-1)%3, consumed before iter t-1's closing barrier.
template <int EPI>
__global__ __launch_bounds__(512, 4) void moe_gemm(
    const unsigned short* __restrict__ Asrc, const unsigned short* __restrict__ Bw,
    const float* __restrict__ bias, unsigned short* __restrict__ hOut,
    float* __restrict__ fOut, const int* __restrict__ arena_token,
    const int* __restrict__ counts, const int* __restrict__ basep,
    int Kd, int Nd, int ny, int Klen) {
    int cpx = gridDim.x >> 3;
    int bid = blockIdx.x;
    int wid = (bid & 7) * cpx + (bid >> 3);
    int nx  = Nd >> 8;                 // BN = 256
    int per = nx * ny * EEXP;
    int ks  = wid / per;
    int rem = wid - ks * per;
    int my  = rem % ny;
    int ne  = rem / ny;
    int e   = ne % EEXP;
    int n   = ne / EEXP;

    int count = counts[e];
    int m0 = my * 128;
    if (m0 >= count) return;
    int base = basep[e];
    int n0 = n * 256;
    int kbase = ks * Klen;
    int tid = threadIdx.x, w = tid >> 6, l = tid & 63;

    float* fOutP = fOut + (size_t)ks * CAP * DDIM;

    // slot: A 8KB @0 (128 rows x 64B), B 16KB @8192 (256 rows x 64B).
    __shared__ __align__(16) char smem[3 * BUF];

    // ---- stage source pointers (pre-swizzled k-chunk, lane-pure); bumped +32 elem/stage ----
    int clog = ((l & 3) ^ ((l >> 3) & 3)) * 8;       // swizzled element offset in K-tile
    const unsigned short *pA0, *pB0, *pB1;
    {
        int ra = m0 + w * 16 + (l >> 2);             // A row (one per wave: 8x16=128)
        int ca = (ra < count) ? ra : (count - 1);
        if (EPI == 1) {
            pA0 = Asrc + (size_t)arena_token[base + ca] * Kd + kbase + clog;
        } else {
            pA0 = Asrc + (size_t)(base + ca) * Kd + kbase + clog;
        }
        int rb = w * 32 + (l >> 2);                  // B rows (two per wave: 8x32=256)
        pB0 = Bw + ((size_t)e * Nd + n0 + rb) * Kd + kbase + clog;
        pB1 = Bw + ((size_t)e * Nd + n0 + rb + 16) * Kd + kbase + clog;
    }

#define STG(sb) do {                                                   \
        char* d_ = smem + (sb) * BUF;                                  \
        gload16(pA0, d_ + w * 1024);                                   \
        gload16(pB0, d_ + 8192 + w * 2048);                            \
        gload16(pB1, d_ + 8192 + w * 2048 + 1024);                     \
        pA0 += 32; pB0 += 32; pB1 += 32;                               \
    } while (0)

    // ---- fragment read addressing (conflict-free swizzle, PMC-verified r13) ----
    int wm = w >> 2, wn = w & 3;                 // 2(M) x 4(N) waves, wave tile 64x64
    int hi = l >> 4;
    int rdc = ((hi ^ ((l >> 1) & 3)) << 4);      // swizzled 16B chunk (lane-pure)
    const char* Ar = smem + (size_t)(wm * 64 + (l & 15)) * 64 + rdc;
    const char* Br = smem + 8192 + (size_t)(wn * 64 + (l & 15)) * 64 + rdc;

    f32x4 acc[4][4];
#pragma unroll
    for (int i = 0; i < 4; ++i)
#pragma unroll
        for (int j = 0; j < 4; ++j) acc[i][j] = (f32x4){0.f, 0.f, 0.f, 0.f};

    int nt = Klen >> 5;                          // 32 or 64, always >= 3
    // prologue: lookahead-2 — tiles 0,1 into slots 0,1.
    STG(0); STG(1);
    asm volatile("s_waitcnt vmcnt(3)" ::: "memory");   // tile0 landed; tile1 in flight
    __builtin_amdgcn_sched_barrier(0);
    __builtin_amdgcn_s_barrier();
    asm volatile("" ::: "memory");

    int cs = 0, ss = 2;   // consume slot t%3; stage tile t+2 into slot (t+2)%3
    for (int t = 0; t < nt; ++t) {
        bool pre = (t + 2 < nt);
        if (pre) STG(ss);
        const char* Ab = Ar + cs * BUF;
        const char* Bb = Br + cs * BUF;
        bf16x8 bq[4];
#pragma unroll
        for (int ni = 0; ni < 4; ++ni) bq[ni] = *(const bf16x8*)(Bb + ni * 1024);
#pragma unroll
        for (int mi = 0; mi < 4; ++mi) {
            bf16x8 a = *(const bf16x8*)(Ab + mi * 1024);
#pragma unroll
            for (int ni = 0; ni < 4; ++ni)
                acc[mi][ni] = __builtin_amdgcn_mfma_f32_16x16x32_bf16(a, bq[ni], acc[mi][ni], 0, 0, 0);
        }
        if (pre) asm volatile("s_waitcnt vmcnt(3)" ::: "memory");  // t+1 landed; t+2 floats
        else     asm volatile("s_waitcnt vmcnt(0)" ::: "memory");  // tail drain
        __builtin_amdgcn_sched_barrier(0);
        __builtin_amdgcn_s_barrier();
        asm volatile("" ::: "memory");
        cs = (cs == 2) ? 0 : cs + 1;
        ss = (ss == 2) ? 0 : ss + 1;
    }
#undef STG

    // Epilogue. C/D layout: col = lane&15, row = (lane>>4)*4 + reg  [m89 verified]
#pragma unroll
    for (int mi = 0; mi < 4; ++mi)
#pragma unroll
        for (int ni = 0; ni < 4; ++ni)
#pragma unroll
            for (int r = 0; r < 4; ++r) {
                int rl = wm * 64 + mi * 16 + hi * 4 + r;
                int gr = m0 + rl;
                if (gr < count) {
                    int col = n0 + wn * 64 + ni * 16 + (l & 15);
                    float v = acc[mi][ni][r];
                    if (EPI == 1) {
                        v += bias[e * Nd + col];
                        v = fmaxf(v, 0.f);
                        hOut[(size_t)(base + gr) * Nd + col] = f2bf(v);
                    } else {
                        fOutP[(size_t)(base + gr) * Nd + col] = v;
                    }
                }
            }
}

// Deterministic combine with 2 K-split partials.
__global__ void combine_k(const float* __restrict__ outP, const float* __restrict__ b2,
                          const int* __restrict__ topk_e, const float* __restrict__ topk_g,
                          const int* __restrict__ pos_of, float* __restrict__ y) {
    int idx = blockIdx.x * blockDim.x + threadIdx.x;
    int s = idx >> 8;
    int c = (idx & 255) * 4;
    int e0 = topk_e[2 * s], e1 = topk_e[2 * s + 1];
    float g0 = topk_g[2 * s], g1 = topk_g[2 * s + 1];
    int p0 = pos_of[2 * s], p1 = pos_of[2 * s + 1];
    const float* P1 = outP + (size_t)CAP * DDIM;
    float4 a0 = *(const float4*)(outP + (size_t)p0 * DDIM + c);
    float4 a1 = *(const float4*)(P1   + (size_t)p0 * DDIM + c);
    float4 b0v = *(const float4*)(outP + (size_t)p1 * DDIM + c);
    float4 b1v = *(const float4*)(P1   + (size_t)p1 * DDIM + c);
    float4 c0 = *(const float4*)(b2 + (size_t)e0 * DDIM + c);
    float4 c1 = *(const float4*)(b2 + (size_t)e1 * DDIM + c);
    float4 r;
    r.x = g0 * (a0.x + a1.x + c0.x) + g1 * (b0v.x + b1v.x + c1.x);
    r.y = g0 * (a0.y + a1.y + c0.y) + g1 * (b0v.y + b1v.y + c1.y);
    r.z = g0 * (a0.z + a1.z + c0.z) + g1 * (b0v.z + b1v.z + c1.z);
    r.w = g0 * (a0.w + a1.w + c0.w) + g1 * (b0v.w + b1v.w + c1.w);
    *(float4*)(y + (size_t)s * DDIM + c) = r;
}

extern "C" void kernel_launch(void* const* d_in, const int* in_sizes, int n_in,
                              void* d_out, int out_size, void* d_ws, size_t ws_size,
                              hipStream_t stream) {
    const float* x      = (const float*)d_in[0];
    const float* gate_w = (const float*)d_in[1];
    const float* w1     = (const float*)d_in[2];
    const float* b1     = (const float*)d_in[3];
    const float* w2     = (const float*)d_in[4];
    const float* b2     = (const float*)d_in[5];

    char* p = (char*)d_ws;
    unsigned short* w1b = (unsigned short*)p;   // 64 MB; reused as outP (2x32MB) after GEMM1
    float* outP         = (float*)p;            p += (size_t)EEXP * FDIM * DDIM * 2;
    unsigned short* w2b = (unsigned short*)p;   p += (size_t)EEXP * FDIM * DDIM * 2;
    unsigned short* xb  = (unsigned short*)p;   p += (size_t)S_TOK * DDIM * 2;
    unsigned short* hA  = (unsigned short*)p;   p += (size_t)CAP * FDIM * 2;
    int*   topk_e       = (int*)p;              p += S_TOK * 2 * 4;
    float* topk_g       = (float*)p;            p += S_TOK * 2 * 4;
    int*   pos_of       = (int*)p;              p += S_TOK * 2 * 4;
    int*   arena_token  = (int*)p;              p += CAP * 4;
    int*   counts       = (int*)p;              p += 64;   // counts+rankctr+basep contiguous
    int*   rankctr      = (int*)p;              p += 64;
    int*   basep        = (int*)p;              p += 64;
    (void)ws_size; (void)in_sizes; (void)n_in; (void)out_size;

    // zero counts/rankctr/basep (48 ints) without a kernel launch
    hipMemsetAsync(counts, 0, 192, stream);

    cvt_both<<<8192, 256, 0, stream>>>(w1, w2, w1b, w2b);

    router_k<<<S_TOK, 64, 0, stream>>>(x, gate_w, xb, topk_e, topk_g, counts);
    scan_k<<<1, 1, 0, stream>>>(counts, basep);
    scatter_k<<<S_TOK / 256, 256, 0, stream>>>(topk_e, rankctr, basep, arena_token, pos_of);

    // GEMM1: grid = nx(16) * ny(32) * E(8) = 4096 (active ~1024 = 2+/CU).
    moe_gemm<1><<<dim3((FDIM / 256) * 32 * EEXP), 512, 0, stream>>>(
        xb, w1b, b1, hA, nullptr, arena_token, counts, basep, DDIM, FDIM, 32, DDIM);
    // GEMM2: K=4096 split 2; grid = nx(4) * ny(32) * E(8) * KS(2) = 2048 (active ~512 = 2/CU).
    moe_gemm<2><<<dim3((DDIM / 256) * 32 * EEXP * 2), 512, 0, stream>>>(
        hA, w2b, nullptr, nullptr, outP, arena_token, counts, basep, FDIM, DDIM, 32, FDIM / 2);

    combine_k<<<S_TOK * DDIM / 4 / 256, 256, 0, stream>>>(
        outP, b2, topk_e, topk_g, pos_of, (float*)d_out);
}

// Round 18
// 438.636 us; speedup vs baseline: 1.1319x; 1.0151x over previous
//
#include <hip/hip_runtime.h>
#include <hip/hip_bf16.h>
#include <stdint.h>

// MoE FFN: B=2,T=2048,D=1024,F=4096,E=8,K=2. S=4096 tokens, 8192 assignments.
#define S_TOK 4096
#define DDIM  1024
#define FDIM  4096
#define EEXP  8
#define CAP   (S_TOK * 2)
#define BUF   24576

typedef __bf16 bf16x8 __attribute__((ext_vector_type(8)));
typedef __bf16 bf16x4 __attribute__((ext_vector_type(4)));
typedef float  f32x4  __attribute__((ext_vector_type(4)));
typedef unsigned short us4 __attribute__((ext_vector_type(4)));

__device__ __forceinline__ unsigned short f2bf(float f) {
    union { float f; unsigned u; } v; v.f = f;
    unsigned u = v.u;
    return (unsigned short)((u + 0x7FFFu + ((u >> 16) & 1u)) >> 16);  // RNE
}

__device__ __forceinline__ float bf2f(unsigned short u) {
    union { unsigned u; float f; } v; v.u = ((unsigned)u) << 16; return v.f;
}

// global -> LDS async copy, 16B/lane. Offset arg MUST stay 0 (r8 lesson).
__device__ __forceinline__ void gload16(const void* g, void* l) {
    auto gp = reinterpret_cast<const __attribute__((address_space(1))) uint32_t*>(
        reinterpret_cast<uintptr_t>(g));
    auto lp = reinterpret_cast<__attribute__((address_space(3))) uint32_t*>(
        static_cast<uint32_t>(reinterpret_cast<uintptr_t>(l)));
    __builtin_amdgcn_global_load_lds(gp, lp, 16, 0, 0);
}

// ---------------- small kernels ----------------

// Both weight tensors in one launch.
__global__ void cvt_both(const float* __restrict__ w1, const float* __restrict__ w2,
                         unsigned short* __restrict__ w1b, unsigned short* __restrict__ w2b) {
    const int n4 = EEXP * FDIM * DDIM / 4;   // per tensor
    int stride = gridDim.x * blockDim.x;
    for (int i = blockIdx.x * blockDim.x + threadIdx.x; i < 2 * n4; i += stride) {
        const float* src = (i < n4) ? w1 : w2;
        unsigned short* dst = (i < n4) ? w1b : w2b;
        int j = (i < n4) ? i : (i - n4);
        float4 v = ((const float4*)src)[j];
        bf16x4 o = { (__bf16)v.x, (__bf16)v.y, (__bf16)v.z, (__bf16)v.w };
        ((bf16x4*)dst)[j] = o;
    }
}

// Router: 256-thread blocks, ONE TOKEN PER WAVE (r18: was 1-wave blocks — scheduler-bound).
// fp32 dot products (must match numpy top-2 selection). Fused x->bf16.
__global__ void router_k(const float* __restrict__ x, const float* __restrict__ gw,
                         unsigned short* __restrict__ xb,
                         int* __restrict__ topk_e, float* __restrict__ topk_g,
                         int* __restrict__ counts) {
    int s = blockIdx.x * 4 + (threadIdx.x >> 6);
    int l = threadIdx.x & 63;
    const float* xr = x + (size_t)s * DDIM;
    unsigned short* xbr = xb + (size_t)s * DDIM;
    float acc[EEXP];
#pragma unroll
    for (int e = 0; e < EEXP; ++e) acc[e] = 0.f;
    for (int i = 0; i < DDIM; i += 64) {
        float xv = xr[i + l];
        xbr[i + l] = f2bf(xv);
#pragma unroll
        for (int e = 0; e < EEXP; ++e) acc[e] = fmaf(xv, gw[e * DDIM + i + l], acc[e]);
    }
#pragma unroll
    for (int e = 0; e < EEXP; ++e)
        for (int off = 32; off > 0; off >>= 1) acc[e] += __shfl_down(acc[e], off, 64);
    if (l == 0) {
        float v0 = -1e30f, v1 = -1e30f; int i0 = 0, i1 = 0;
#pragma unroll
        for (int e = 0; e < EEXP; ++e) {
            float v = acc[e];
            if (v > v0)      { v1 = v0; i1 = i0; v0 = v; i0 = e; }
            else if (v > v1) { v1 = v;  i1 = e; }
        }
        float t = expf(v1 - v0);
        float d = 1.f + t;
        topk_e[2 * s] = i0; topk_e[2 * s + 1] = i1;
        topk_g[2 * s] = 1.f / d; topk_g[2 * s + 1] = t / d;
        atomicAdd(&counts[i0], 1);
        atomicAdd(&counts[i1], 1);
    }
}

__global__ void scan_k(const int* __restrict__ counts, int* __restrict__ basep) {
    if (threadIdx.x == 0) {
        int b = 0;
        for (int e = 0; e < EEXP; ++e) { basep[e] = b; b += counts[e]; }
    }
}

__global__ void scatter_k(const int* __restrict__ topk_e, int* __restrict__ rankctr,
                          const int* __restrict__ basep, int* __restrict__ arena_token,
                          int* __restrict__ pos_of) {
    int s = blockIdx.x * blockDim.x + threadIdx.x;
    if (s >= S_TOK) return;
#pragma unroll
    for (int t = 0; t < 2; ++t) {
        int e = topk_e[2 * s + t];
        int r = atomicAdd(&rankctr[e], 1);
        int p = basep[e] + r;
        arena_token[p] = s;
        pos_of[2 * s + t] = p;
    }
}

// ---------------- MFMA GEMM: BM=128 x BN=256, BK=32, 8 waves, triple-buffer lookahead-2 ----
// r13/r17-proven config (measured optimum across 11 structural variants): staging-bound at
// the chip's ~6 TB/s staged-byte ceiling; 768MB staged volume is the feasible minimum at
// 2 blocks/CU. Pipeline: 3 slots, lookahead 2, vmcnt(3) steady-state close, vmcnt(0) tail.
// r18 delta: EPI==2 writes bf16 partials (halves G2 write + combine read traffic).
template <int EPI>
__global__ __launch_bounds__(512, 4) void moe_gemm(
    const unsigned short* __restrict__ Asrc, const unsigned short* __restrict__ Bw,
    const float* __restrict__ bias, unsigned short* __restrict__ hOut,
    unsigned short* __restrict__ outH, const int* __restrict__ arena_token,
    const int* __restrict__ counts, const int* __restrict__ basep,
    int Kd, int Nd, int ny, int Klen) {
    int cpx = gridDim.x >> 3;
    int bid = blockIdx.x;
    int wid = (bid & 7) * cpx + (bid >> 3);
    int nx  = Nd >> 8;                 // BN = 256
    int per = nx * ny * EEXP;
    int ks  = wid / per;
    int rem = wid - ks * per;
    int my  = rem % ny;
    int ne  = rem / ny;
    int e   = ne % EEXP;
    int n   = ne / EEXP;

    int count = counts[e];
    int m0 = my * 128;
    if (m0 >= count) return;
    int base = basep[e];
    int n0 = n * 256;
    int kbase = ks * Klen;
    int tid = threadIdx.x, w = tid >> 6, l = tid & 63;

    unsigned short* outP = outH + (size_t)ks * CAP * DDIM;

    // slot: A 8KB @0 (128 rows x 64B), B 16KB @8192 (256 rows x 64B).
    __shared__ __align__(16) char smem[3 * BUF];

    // ---- stage source pointers (pre-swizzled k-chunk, lane-pure); bumped +32 elem/stage ----
    int clog = ((l & 3) ^ ((l >> 3) & 3)) * 8;       // swizzled element offset in K-tile
    const unsigned short *pA0, *pB0, *pB1;
    {
        int ra = m0 + w * 16 + (l >> 2);             // A row (one per wave: 8x16=128)
        int ca = (ra < count) ? ra : (count - 1);
        if (EPI == 1) {
            pA0 = Asrc + (size_t)arena_token[base + ca] * Kd + kbase + clog;
        } else {
            pA0 = Asrc + (size_t)(base + ca) * Kd + kbase + clog;
        }
        int rb = w * 32 + (l >> 2);                  // B rows (two per wave: 8x32=256)
        pB0 = Bw + ((size_t)e * Nd + n0 + rb) * Kd + kbase + clog;
        pB1 = Bw + ((size_t)e * Nd + n0 + rb + 16) * Kd + kbase + clog;
    }

#define STG(sb) do {                                                   \
        char* d_ = smem + (sb) * BUF;                                  \
        gload16(pA0, d_ + w * 1024);                                   \
        gload16(pB0, d_ + 8192 + w * 2048);                            \
        gload16(pB1, d_ + 8192 + w * 2048 + 1024);                     \
        pA0 += 32; pB0 += 32; pB1 += 32;                               \
    } while (0)

    // ---- fragment read addressing (conflict-free swizzle, PMC-verified r13/r17) ----
    int wm = w >> 2, wn = w & 3;                 // 2(M) x 4(N) waves, wave tile 64x64
    int hi = l >> 4;
    int rdc = ((hi ^ ((l >> 1) & 3)) << 4);      // swizzled 16B chunk (lane-pure)
    const char* Ar = smem + (size_t)(wm * 64 + (l & 15)) * 64 + rdc;
    const char* Br = smem + 8192 + (size_t)(wn * 64 + (l & 15)) * 64 + rdc;

    f32x4 acc[4][4];
#pragma unroll
    for (int i = 0; i < 4; ++i)
#pragma unroll
        for (int j = 0; j < 4; ++j) acc[i][j] = (f32x4){0.f, 0.f, 0.f, 0.f};

    int nt = Klen >> 5;                          // 32 or 64, always >= 3
    // prologue: lookahead-2 — tiles 0,1 into slots 0,1.
    STG(0); STG(1);
    asm volatile("s_waitcnt vmcnt(3)" ::: "memory");   // tile0 landed; tile1 in flight
    __builtin_amdgcn_sched_barrier(0);
    __builtin_amdgcn_s_barrier();
    asm volatile("" ::: "memory");

    int cs = 0, ss = 2;   // consume slot t%3; stage tile t+2 into slot (t+2)%3
    for (int t = 0; t < nt; ++t) {
        bool pre = (t + 2 < nt);
        if (pre) STG(ss);
        const char* Ab = Ar + cs * BUF;
        const char* Bb = Br + cs * BUF;
        bf16x8 bq[4];
#pragma unroll
        for (int ni = 0; ni < 4; ++ni) bq[ni] = *(const bf16x8*)(Bb + ni * 1024);
#pragma unroll
        for (int mi = 0; mi < 4; ++mi) {
            bf16x8 a = *(const bf16x8*)(Ab + mi * 1024);
#pragma unroll
            for (int ni = 0; ni < 4; ++ni)
                acc[mi][ni] = __builtin_amdgcn_mfma_f32_16x16x32_bf16(a, bq[ni], acc[mi][ni], 0, 0, 0);
        }
        if (pre) asm volatile("s_waitcnt vmcnt(3)" ::: "memory");  // t+1 landed; t+2 floats
        else     asm volatile("s_waitcnt vmcnt(0)" ::: "memory");  // tail drain
        __builtin_amdgcn_sched_barrier(0);
        __builtin_amdgcn_s_barrier();
        asm volatile("" ::: "memory");
        cs = (cs == 2) ? 0 : cs + 1;
        ss = (ss == 2) ? 0 : ss + 1;
    }
#undef STG

    // Epilogue. C/D layout: col = lane&15, row = (lane>>4)*4 + reg  [m89 verified]
#pragma unroll
    for (int mi = 0; mi < 4; ++mi)
#pragma unroll
        for (int ni = 0; ni < 4; ++ni)
#pragma unroll
            for (int r = 0; r < 4; ++r) {
                int rl = wm * 64 + mi * 16 + hi * 4 + r;
                int gr = m0 + rl;
                if (gr < count) {
                    int col = n0 + wn * 64 + ni * 16 + (l & 15);
                    float v = acc[mi][ni][r];
                    if (EPI == 1) {
                        v += bias[e * Nd + col];
                        v = fmaxf(v, 0.f);
                        hOut[(size_t)(base + gr) * Nd + col] = f2bf(v);
                    } else {
                        outP[(size_t)(base + gr) * Nd + col] = f2bf(v);
                    }
                }
            }
}

// Deterministic combine with 2 bf16 K-split partials.
__global__ void combine_k(const unsigned short* __restrict__ outH, const float* __restrict__ b2,
                          const int* __restrict__ topk_e, const float* __restrict__ topk_g,
                          const int* __restrict__ pos_of, float* __restrict__ y) {
    int idx = blockIdx.x * blockDim.x + threadIdx.x;
    int s = idx >> 8;
    int c = (idx & 255) * 4;
    int e0 = topk_e[2 * s], e1 = topk_e[2 * s + 1];
    float g0 = topk_g[2 * s], g1 = topk_g[2 * s + 1];
    int p0 = pos_of[2 * s], p1 = pos_of[2 * s + 1];
    const unsigned short* P1 = outH + (size_t)CAP * DDIM;
    us4 a0 = *(const us4*)(outH + (size_t)p0 * DDIM + c);
    us4 a1 = *(const us4*)(P1   + (size_t)p0 * DDIM + c);
    us4 b0v = *(const us4*)(outH + (size_t)p1 * DDIM + c);
    us4 b1v = *(const us4*)(P1   + (size_t)p1 * DDIM + c);
    float4 c0 = *(const float4*)(b2 + (size_t)e0 * DDIM + c);
    float4 c1 = *(const float4*)(b2 + (size_t)e1 * DDIM + c);
    float4 r;
    r.x = g0 * (bf2f(a0[0]) + bf2f(a1[0]) + c0.x) + g1 * (bf2f(b0v[0]) + bf2f(b1v[0]) + c1.x);
    r.y = g0 * (bf2f(a0[1]) + bf2f(a1[1]) + c0.y) + g1 * (bf2f(b0v[1]) + bf2f(b1v[1]) + c1.y);
    r.z = g0 * (bf2f(a0[2]) + bf2f(a1[2]) + c0.z) + g1 * (bf2f(b0v[2]) + bf2f(b1v[2]) + c1.z);
    r.w = g0 * (bf2f(a0[3]) + bf2f(a1[3]) + c0.w) + g1 * (bf2f(b0v[3]) + bf2f(b1v[3]) + c1.w);
    *(float4*)(y + (size_t)s * DDIM + c) = r;
}

extern "C" void kernel_launch(void* const* d_in, const int* in_sizes, int n_in,
                              void* d_out, int out_size, void* d_ws, size_t ws_size,
                              hipStream_t stream) {
    const float* x      = (const float*)d_in[0];
    const float* gate_w = (const float*)d_in[1];
    const float* w1     = (const float*)d_in[2];
    const float* b1     = (const float*)d_in[3];
    const float* w2     = (const float*)d_in[4];
    const float* b2     = (const float*)d_in[5];

    char* p = (char*)d_ws;
    unsigned short* w1b = (unsigned short*)p;   // 64 MB; reused as outH (2x16MB bf16) after G1
    unsigned short* outH = (unsigned short*)p;  p += (size_t)EEXP * FDIM * DDIM * 2;
    unsigned short* w2b = (unsigned short*)p;   p += (size_t)EEXP * FDIM * DDIM * 2;
    unsigned short* xb  = (unsigned short*)p;   p += (size_t)S_TOK * DDIM * 2;
    unsigned short* hA  = (unsigned short*)p;   p += (size_t)CAP * FDIM * 2;
    int*   topk_e       = (int*)p;              p += S_TOK * 2 * 4;
    float* topk_g       = (float*)p;            p += S_TOK * 2 * 4;
    int*   pos_of       = (int*)p;              p += S_TOK * 2 * 4;
    int*   arena_token  = (int*)p;              p += CAP * 4;
    int*   counts       = (int*)p;              p += 64;   // counts+rankctr+basep contiguous
    int*   rankctr      = (int*)p;              p += 64;
    int*   basep        = (int*)p;              p += 64;
    (void)ws_size; (void)in_sizes; (void)n_in; (void)out_size;

    hipMemsetAsync(counts, 0, 192, stream);

    cvt_both<<<8192, 256, 0, stream>>>(w1, w2, w1b, w2b);

    router_k<<<S_TOK / 4, 256, 0, stream>>>(x, gate_w, xb, topk_e, topk_g, counts);
    scan_k<<<1, 1, 0, stream>>>(counts, basep);
    scatter_k<<<S_TOK / 256, 256, 0, stream>>>(topk_e, rankctr, basep, arena_token, pos_of);

    // GEMM1: grid = nx(16) * ny(32) * E(8) = 4096 (active ~1024 = 2+/CU).
    moe_gemm<1><<<dim3((FDIM / 256) * 32 * EEXP), 512, 0, stream>>>(
        xb, w1b, b1, hA, nullptr, arena_token, counts, basep, DDIM, FDIM, 32, DDIM);
    // GEMM2: K=4096 split 2; grid = nx(4) * ny(32) * E(8) * KS(2) = 2048 (active ~512 = 2/CU).
    moe_gemm<2><<<dim3((DDIM / 256) * 32 * EEXP * 2), 512, 0, stream>>>(
        hA, w2b, nullptr, nullptr, outH, arena_token, counts, basep, FDIM, DDIM, 32, FDIM / 2);

    combine_k<<<S_TOK * DDIM / 4 / 256, 256, 0, stream>>>(
        outH, b2, topk_e, topk_g, pos_of, (float*)d_out);
}